// Round 6
// baseline (419.830 us; speedup 1.0000x reference)
//
#include <hip/hip_runtime.h>
#include <hip/hip_bf16.h>
#include <math.h>

// Problem constants (match reference)
#define BATCH 4
#define SEQ   2048
#define DMODEL 768
#define NHEAD 12
#define HS    64
#define HID   3072   // 4*DMODEL
#define NROWS (BATCH*SEQ)   // 8192
#define QKVN  (3*DMODEL)    // 2304
#define EPS   1e-6f

typedef __attribute__((ext_vector_type(8))) short bf16x8;
typedef __attribute__((ext_vector_type(4))) float f32x4;

__device__ inline ushort f2b(float f) {
    union { float f; unsigned u; } x; x.f = f;
    unsigned u = x.u;
    unsigned r = (u + 0x7FFFu + ((u >> 16) & 1u)) >> 16;
    return (ushort)r;
}

// async global->LDS, 16B per lane (m97)
#define GLDS16(g, l) __builtin_amdgcn_global_load_lds( \
    (const __attribute__((address_space(1))) void*)(g), \
    (__attribute__((address_space(3))) void*)(l), 16, 0, 0)

// ---------------- Weight convert+transpose: fp32 [K][N] -> bf16 [N][K] ----------------
__global__ __launch_bounds__(256) void convert_w4(const float* __restrict__ p0,
                                                  const float* __restrict__ p1,
                                                  const float* __restrict__ p2,
                                                  const float* __restrict__ p3,
                                                  ushort* __restrict__ out) {
    const float* srcs[4] = { p0, p1, p2, p3 };
    const float* in = srcs[blockIdx.z];
    ushort* dst = out + (size_t)blockIdx.z * DMODEL * DMODEL;
    __shared__ float tile[32][33];
    const int bx = blockIdx.x * 32;  // N
    const int by = blockIdx.y * 32;  // K
    const int tx = threadIdx.x & 31, ty = threadIdx.x >> 5;
    #pragma unroll
    for (int i = 0; i < 32; i += 8)
        tile[ty + i][tx] = in[(size_t)(by + ty + i) * DMODEL + bx + tx];
    __syncthreads();
    #pragma unroll
    for (int i = 0; i < 32; i += 8)
        dst[(size_t)(bx + ty + i) * DMODEL + by + tx] = f2b(tile[tx][ty + i]);
}

__global__ __launch_bounds__(256) void convert_w(const float* __restrict__ in,
                                                 ushort* __restrict__ out,
                                                 int K, int N) {
    __shared__ float tile[32][33];
    const int bx = blockIdx.x * 32;  // N
    const int by = blockIdx.y * 32;  // K
    const int tx = threadIdx.x & 31, ty = threadIdx.x >> 5;
    #pragma unroll
    for (int i = 0; i < 32; i += 8)
        tile[ty + i][tx] = in[(size_t)(by + ty + i) * N + bx + tx];
    __syncthreads();
    #pragma unroll
    for (int i = 0; i < 32; i += 8)
        out[(size_t)(bx + ty + i) * K + by + tx] = f2b(tile[tx][ty + i]);
}

// ---------------- V transpose: v[b][s][h*64+d] (stride QKVN) -> vt[(bh*64+d)][s] ----------------
__global__ __launch_bounds__(256) void transpose_v(const ushort* __restrict__ v,
                                                   ushort* __restrict__ vt) {
    const int st = blockIdx.x;   // key tile (64 rows)
    const int bh = blockIdx.y;
    const int b = bh / NHEAD, h = bh % NHEAD;
    const ushort* src = v + ((size_t)b * SEQ) * QKVN + h * HS;
    ushort* dst = vt + ((size_t)bh * HS) * SEQ;
    __shared__ ushort t[64][65];
    const int col = threadIdx.x & 63;
    const int r0  = (threadIdx.x >> 6) * 16;
    #pragma unroll
    for (int i = 0; i < 16; ++i)
        t[col][r0 + i] = src[(size_t)(st * 64 + r0 + i) * QKVN + col];
    __syncthreads();
    #pragma unroll
    for (int i = 0; i < 16; ++i)
        dst[(size_t)(r0 + i) * SEQ + st * 64 + col] = t[r0 + i][col];
}

// ---------------- LayerNorm (ddof=1), fp32 in -> bf16 out ----------------
__global__ __launch_bounds__(256) void ln_kernel(const float* __restrict__ x,
                                                 const float* __restrict__ gamma,
                                                 const float* __restrict__ beta,
                                                 ushort* __restrict__ out) {
    const int row = blockIdx.x;
    const float* xr = x + (size_t)row * DMODEL;
    float s = 0.f, s2 = 0.f;
    for (int i = threadIdx.x; i < DMODEL; i += 256) {
        float v = xr[i];
        s += v; s2 += v * v;
    }
    for (int off = 32; off > 0; off >>= 1) {
        s  += __shfl_down(s,  off, 64);
        s2 += __shfl_down(s2, off, 64);
    }
    __shared__ float shs[4], shs2[4];
    int wid = threadIdx.x >> 6, lane = threadIdx.x & 63;
    if (lane == 0) { shs[wid] = s; shs2[wid] = s2; }
    __syncthreads();
    __shared__ float smean, srstd;
    if (threadIdx.x == 0) {
        float S  = shs[0] + shs[1] + shs[2] + shs[3];
        float S2 = shs2[0] + shs2[1] + shs2[2] + shs2[3];
        float mean = S / DMODEL;
        float var  = (S2 - DMODEL * mean * mean) / (DMODEL - 1);
        smean = mean;
        srstd = rsqrtf(var + EPS);
    }
    __syncthreads();
    float mean = smean, rstd = srstd;
    ushort* orow = out + (size_t)row * DMODEL;
    for (int i = threadIdx.x; i < DMODEL; i += 256) {
        orow[i] = f2b(gamma[i] * (xr[i] - mean) * rstd + beta[i]);
    }
}

// ---------------- gemm_mfma: 64x128 tile, BK=64, per-wave 32x64 (kept for N=768) ----------------
// r10 geometry: 48KB dbuf, 3 blocks/CU; grids with N=768 are 768 blocks = 3/CU.
#define GN 128
#define GK 64
#define GM 64
__global__ __launch_bounds__(256, 3) void gemm_mfma(const ushort* __restrict__ A,
                                                    const ushort* __restrict__ Bt,
                                                    const float* __restrict__ bias,
                                                    const float* __restrict__ res,
                                                    float* __restrict__ C,
                                                    ushort* __restrict__ Cb,
                                                    int M, int N, int K, int do_relu,
                                                    int scale_q) {
    __shared__ ushort As[2][GM * GK];
    __shared__ ushort Bs[2][GN * GK];
    const int tid  = threadIdx.x;
    const int lane = tid & 63, wave = tid >> 6;
    const int l16  = lane & 15, quad = lane >> 4;
    const int wr = wave >> 1, wc = wave & 1;

    // XCD-aware swizzle: give each XCD a contiguous row-major chunk
    const int nwg = gridDim.x * gridDim.y;
    int id = blockIdx.y * gridDim.x + blockIdx.x;
    if ((nwg & 7) == 0) {
        const int chunk = nwg >> 3;
        id = (id & 7) * chunk + (id >> 3);
    }
    const int bx = id % gridDim.x;
    const int by = id / gridDim.x;
    const int row0 = by * GM, col0 = bx * GN;

    f32x4 acc[2][4];
    #pragma unroll
    for (int i = 0; i < 2; ++i)
        #pragma unroll
        for (int j = 0; j < 4; ++j) acc[i][j] = (f32x4){0.f, 0.f, 0.f, 0.f};

    // staging: LDS chunk c=(m<<3)|j  <-  global chunk j^(m&7) of row m
    const ushort* Asrc[2];
    const ushort* Bsrc[4];
    #pragma unroll
    for (int i = 0; i < 2; ++i) {
        int c = tid + i * 256, m = c >> 3, j = c & 7;
        Asrc[i] = A + (size_t)(row0 + m) * K + (j ^ (m & 7)) * 8;
    }
    #pragma unroll
    for (int i = 0; i < 4; ++i) {
        int c = tid + i * 256, m = c >> 3, j = c & 7;
        Bsrc[i] = Bt + (size_t)(col0 + m) * K + (j ^ (m & 7)) * 8;
    }

    const int nk = K / GK;
    // prologue: stage K-tile 0 into buf 0
    #pragma unroll
    for (int i = 0; i < 2; ++i) GLDS16(Asrc[i], &As[0][(tid + i * 256) * 8]);
    #pragma unroll
    for (int i = 0; i < 4; ++i)  GLDS16(Bsrc[i], &Bs[0][(tid + i * 256) * 8]);

    for (int kt = 0; kt < nk; ++kt) {
        const int p = kt & 1;
        __syncthreads();   // drains buf[p] loads; all waves done reading buf[p^1]
        if (kt + 1 < nk) {
            const int k1 = (kt + 1) * GK;
            #pragma unroll
            for (int i = 0; i < 2; ++i) GLDS16(Asrc[i] + k1, &As[p ^ 1][(tid + i * 256) * 8]);
            #pragma unroll
            for (int i = 0; i < 4; ++i)  GLDS16(Bsrc[i] + k1, &Bs[p ^ 1][(tid + i * 256) * 8]);
        }

        #pragma unroll
        for (int s = 0; s < 2; ++s) {
            bf16x8 af[2], bfr[4];
            #pragma unroll
            for (int i = 0; i < 2; ++i) {
                int m = wr * 32 + i * 16 + l16;
                af[i] = *(const bf16x8*)&As[p][(m * 8 + (((s << 2) | quad) ^ (m & 7))) * 8];
            }
            #pragma unroll
            for (int j = 0; j < 4; ++j) {
                int n = wc * 64 + j * 16 + l16;
                bfr[j] = *(const bf16x8*)&Bs[p][(n * 8 + (((s << 2) | quad) ^ (n & 7))) * 8];
            }
            #pragma unroll
            for (int i = 0; i < 2; ++i)
                #pragma unroll
                for (int j = 0; j < 4; ++j)
                    acc[i][j] = __builtin_amdgcn_mfma_f32_16x16x32_bf16(af[i], bfr[j], acc[i][j], 0, 0, 0);
        }
    }

    // epilogue: C/D layout col=l16, row=quad*4+r
    #pragma unroll
    for (int i = 0; i < 2; ++i) {
        #pragma unroll
        for (int r = 0; r < 4; ++r) {
            int row = row0 + wr * 32 + i * 16 + quad * 4 + r;
            #pragma unroll
            for (int j = 0; j < 4; ++j) {
                int col = col0 + wc * 64 + j * 16 + l16;
                float v = acc[i][j][r];
                if (bias) v += bias[col];
                if (do_relu) v = fmaxf(v, 0.f);
                if (scale_q && col < DMODEL) v *= 0.125f;  // fold 1/sqrt(hs) into Q
                if (res) v += res[(size_t)row * N + col];
                if (Cb) Cb[(size_t)row * N + col] = f2b(v);
                else    C [(size_t)row * N + col] = v;
            }
        }
    }
}

// ---------------- gemm_big: 128x128 tile, BK=32, TRI-buffer + counted vmcnt ----------------
// r13: r5 proved layout is conflict-free (4.7M -> 0) but got SLOWER (85->92.5)
// -> the bottleneck is the __syncthreads barrier DRAIN (s_waitcnt vmcnt(0)):
// every K-step the just-issued prefetch must fully land after only ~16 MFMAs
// of cover. BK=32 doubled the drain count vs r2's BK=64 (24 vs 12) -> slower
// despite less LDS traffic. Fix = T4 counted vmcnt: 3 buffers (48KB, 3
// blocks/CU), per K-step wait ONLY tile t's 4 loads (vmcnt(4)), raw
// s_barrier (no drain), then issue tile t+2. Tile t's loads get ~2 compute
// windows of latency cover instead of <1; vmcnt never 0 in the main loop.
// Race safety: a wave's MFMAs consume its ds_reads (compiler lgkm waits), so
// passing the barrier implies reads of buf[(t-1)%3] are done before
// STAGE(t+2) overwrites it. Layout/staging/epilogue byte-identical to r5.
#define HM 128
#define HN 128
#define HK 32
__global__ __launch_bounds__(256, 3) void gemm_big(const ushort* __restrict__ A,
                                                   const ushort* __restrict__ Bt,
                                                   const float* __restrict__ bias,
                                                   const float* __restrict__ res,
                                                   float* __restrict__ C,
                                                   ushort* __restrict__ Cb,
                                                   int M, int N, int K, int do_relu,
                                                   int scale_q) {
    __shared__ ushort As[3][HM * HK];   // 3 x 8 KB
    __shared__ ushort Bs[3][HN * HK];   // 3 x 8 KB  -> 48 KB total
    const int tid  = threadIdx.x;
    const int lane = tid & 63, wave = tid >> 6;
    const int l16  = lane & 15, quad = lane >> 4;
    const int wr = wave >> 1, wc = wave & 1;

    const int nwg = gridDim.x * gridDim.y;
    int id = blockIdx.y * gridDim.x + blockIdx.x;
    if ((nwg & 7) == 0) {
        const int chunk = nwg >> 3;
        id = (id & 7) * chunk + (id >> 3);
    }
    const int bx = id % gridDim.x;
    const int by = id / gridDim.x;
    const int row0 = by * HM, col0 = bx * HN;

    f32x4 acc[4][4];
    #pragma unroll
    for (int i = 0; i < 4; ++i)
        #pragma unroll
        for (int j = 0; j < 4; ++j) acc[i][j] = (f32x4){0.f, 0.f, 0.f, 0.f};

    // staging: LDS chunk c = lr*8+pos holds global (m = 2*lr + (p>>2), j = p&3)
    // where p = pos ^ (lr&7)   [zero-conflict row-pair layout, verified r5]
    const ushort* Asrc[2];
    const ushort* Bsrc[2];
    #pragma unroll
    for (int i = 0; i < 2; ++i) {
        int c = tid + i * 256;
        int lr = c >> 3, pp = (c & 7) ^ (lr & 7);
        int m = lr * 2 + (pp >> 2), j = pp & 3;
        Asrc[i] = A  + (size_t)(row0 + m) * K + j * 8;
        Bsrc[i] = Bt + (size_t)(col0 + m) * K + j * 8;
    }

    const int nk = K / HK;   // K=768 -> 24 (always >= 3 here)

    // 4 vmcnt-instructions per tile-stage (A0,A1,B0,B1)
#define STAGE_BIG(kt, b) do { \
    const int _k = (kt) * HK; \
    GLDS16(Asrc[0] + _k, &As[b][tid * 8]); \
    GLDS16(Asrc[1] + _k, &As[b][(tid + 256) * 8]); \
    GLDS16(Bsrc[0] + _k, &Bs[b][tid * 8]); \
    GLDS16(Bsrc[1] + _k, &Bs[b][(tid + 256) * 8]); \
} while (0)

    STAGE_BIG(0, 0);
    STAGE_BIG(1, 1);

    int pc = 0, pn = 1, ps = 2;   // compute / next / stage-target buffers
    for (int t = 0; t < nk; ++t) {
        // wait tile t only: tile t+1's 4 loads stay in flight
        if (t + 1 < nk) asm volatile("s_waitcnt vmcnt(4)" ::: "memory");
        else            asm volatile("s_waitcnt vmcnt(0)" ::: "memory");
        __builtin_amdgcn_s_barrier();
        if (t + 2 < nk) STAGE_BIG(t + 2, ps);

        bf16x8 af[4], bfr[4];
        #pragma unroll
        for (int i = 0; i < 4; ++i) {
            int m = wr * 64 + i * 16 + l16;
            int ch = (m >> 1) * 8 + ((((m & 1) << 2) | quad) ^ ((m >> 1) & 7));
            af[i] = *(const bf16x8*)&As[pc][ch * 8];
        }
        #pragma unroll
        for (int j = 0; j < 4; ++j) {
            int n = wc * 64 + j * 16 + l16;
            int ch = (n >> 1) * 8 + ((((n & 1) << 2) | quad) ^ ((n >> 1) & 7));
            bfr[j] = *(const bf16x8*)&Bs[pc][ch * 8];
        }
        #pragma unroll
        for (int i = 0; i < 4; ++i)
            #pragma unroll
            for (int j = 0; j < 4; ++j)
                acc[i][j] = __builtin_amdgcn_mfma_f32_16x16x32_bf16(af[i], bfr[j], acc[i][j], 0, 0, 0);

        int tmp = pc; pc = pn; pn = ps; ps = tmp;
    }

    // epilogue: C/D layout col=l16, row=quad*4+r
    #pragma unroll
    for (int i = 0; i < 4; ++i) {
        #pragma unroll
        for (int r = 0; r < 4; ++r) {
            int row = row0 + wr * 64 + i * 16 + quad * 4 + r;
            #pragma unroll
            for (int j = 0; j < 4; ++j) {
                int col = col0 + wc * 64 + j * 16 + l16;
                float v = acc[i][j][r];
                if (bias) v += bias[col];
                if (do_relu) v = fmaxf(v, 0.f);
                if (scale_q && col < DMODEL) v *= 0.125f;  // fold 1/sqrt(hs) into Q
                if (res) v += res[(size_t)row * N + col];
                if (Cb) Cb[(size_t)row * N + col] = f2b(v);
                else    C [(size_t)row * N + col] = v;
            }
        }
    }
}

// ---------------- Flash attention: paired q-tiles, GLDS staging, dbuf ----------------
#define TQ 64
#define TK 64
#define PPAD 72
#define NQT (SEQ / TQ)   // 32

__global__ __launch_bounds__(256, 3) void fattn_kernel(const ushort* __restrict__ q,
                                                       const ushort* __restrict__ k,
                                                       const ushort* __restrict__ vt,
                                                       ushort* __restrict__ o,
                                                       int ldqkv) {
    const int pair = blockIdx.x;             // 0..15
    const int qts[2] = { pair, NQT - 1 - pair };
    const int bh = blockIdx.y;
    const int b = bh / NHEAD, h = bh % NHEAD;
    const int tid  = threadIdx.x;
    const int wave = tid >> 6;
    const int lane = tid & 63;
    const int l16  = lane & 15;
    const int quad = lane >> 4;

    __shared__ ushort Ks[2][TK * 64];    // 8 KB per buffer, packed [key][8 chunks]
    __shared__ ushort Vs[2][HS * 64];    // 8 KB per buffer, packed [d][8 chunks]
    __shared__ ushort Ps[4][16][PPAD];   // per-wave P[q][key] (wave-private)

    const size_t base  = ((size_t)b * SEQ) * ldqkv + (size_t)h * HS;
    const size_t baseO = ((size_t)b * SEQ) * DMODEL + (size_t)h * HS;
    const ushort* vth = vt + ((size_t)bh * HS) * SEQ;

    const int r0 = tid >> 3, j0 = (tid & 7) ^ (r0 & 7);
    const int r1 = (tid + 256) >> 3, j1 = (tid & 7) ^ (r1 & 7);
    const ushort* Ksrc0 = k + base + (size_t)r0 * ldqkv + j0 * 8;
    const ushort* Ksrc1 = k + base + (size_t)r1 * ldqkv + j1 * 8;
    const ushort* Vsrc0 = vth + (size_t)r0 * SEQ + j0 * 8;
    const ushort* Vsrc1 = vth + (size_t)r1 * SEQ + j1 * 8;

    bf16x8 qf[2][2];
    #pragma unroll
    for (int t = 0; t < 2; ++t) {
        int qrow = qts[t] * TQ + wave * 16 + l16;
        const ushort* qp = q + base + (size_t)qrow * ldqkv + quad * 8;
        qf[t][0] = *(const bf16x8*)(qp);
        qf[t][1] = *(const bf16x8*)(qp + 32);
    }

    f32x4 Oacc[2][4];
    float lrow[2][4];
    #pragma unroll
    for (int t = 0; t < 2; ++t) {
        #pragma unroll
        for (int f = 0; f < 4; ++f) Oacc[t][f] = (f32x4){0.f, 0.f, 0.f, 0.f};
        #pragma unroll
        for (int r = 0; r < 4; ++r) lrow[t][r] = 0.f;
    }

    const int ktiles = qts[1] + 1;
    GLDS16(Ksrc0, &Ks[0][tid * 8]);
    GLDS16(Ksrc1, &Ks[0][(tid + 256) * 8]);
    GLDS16(Vsrc0, &Vs[0][tid * 8]);
    GLDS16(Vsrc1, &Vs[0][(tid + 256) * 8]);

    for (int kt = 0; kt < ktiles; ++kt) {
        const int p = kt & 1;
        __syncthreads();   // drains buf[p] (in flight since last compute phase)
        if (kt + 1 < ktiles) {
            const size_t ko = (size_t)(kt + 1) * TK;
            GLDS16(Ksrc0 + ko * ldqkv, &Ks[p ^ 1][tid * 8]);
            GLDS16(Ksrc1 + ko * ldqkv, &Ks[p ^ 1][(tid + 256) * 8]);
            GLDS16(Vsrc0 + ko,         &Vs[p ^ 1][tid * 8]);
            GLDS16(Vsrc1 + ko,         &Vs[p ^ 1][(tid + 256) * 8]);
        }

        bf16x8 kb[4][2], vb[4][2];
        #pragma unroll
        for (int f = 0; f < 4; ++f) {
            int row = f * 16 + l16;
            kb[f][0] = *(const bf16x8*)&Ks[p][(row * 8 + (quad ^ (row & 7))) * 8];
            kb[f][1] = *(const bf16x8*)&Ks[p][(row * 8 + ((4 | quad) ^ (row & 7))) * 8];
            vb[f][0] = *(const bf16x8*)&Vs[p][(row * 8 + (quad ^ (row & 7))) * 8];
            vb[f][1] = *(const bf16x8*)&Vs[p][(row * 8 + ((4 | quad) ^ (row & 7))) * 8];
        }

        #pragma unroll
        for (int t = 0; t < 2; ++t) {
            const int qt = qts[t];
            if (kt > qt) continue;   // wave-uniform; only t=0 can skip

            f32x4 S[4];
            #pragma unroll
            for (int f = 0; f < 4; ++f) {
                f32x4 a = (f32x4){0.f, 0.f, 0.f, 0.f};
                a = __builtin_amdgcn_mfma_f32_16x16x32_bf16(qf[t][0], kb[f][0], a, 0, 0, 0);
                a = __builtin_amdgcn_mfma_f32_16x16x32_bf16(qf[t][1], kb[f][1], a, 0, 0, 0);
                S[f] = a;
            }

            const int qrow_base = qt * TQ + wave * 16 + quad * 4;
            if (kt == qt) {
                #pragma unroll
                for (int f = 0; f < 4; ++f) {
                    int key = kt * TK + f * 16 + l16;
                    #pragma unroll
                    for (int r = 0; r < 4; ++r)
                        if (key > qrow_base + r) S[f][r] = -INFINITY;
                }
            }

            #pragma unroll
            for (int f = 0; f < 4; ++f) {
                #pragma unroll
                for (int r = 0; r < 4; ++r) {
                    float pv = __expf(S[f][r]);
                    S[f][r] = pv;
                    lrow[t][r] += pv;
                }
            }

            #pragma unroll
            for (int f = 0; f < 4; ++f)
                #pragma unroll
                for (int r = 0; r < 4; ++r)
                    Ps[wave][quad * 4 + r][f * 16 + l16] = f2b(S[f][r]);

            bf16x8 pa0 = *(const bf16x8*)&Ps[wave][l16][quad * 8];
            bf16x8 pa1 = *(const bf16x8*)&Ps[wave][l16][32 + quad * 8];
            #pragma unroll
            for (int f = 0; f < 4; ++f) {
                Oacc[t][f] = __builtin_amdgcn_mfma_f32_16x16x32_bf16(pa0, vb[f][0], Oacc[t][f], 0, 0, 0);
                Oacc[t][f] = __builtin_amdgcn_mfma_f32_16x16x32_bf16(pa1, vb[f][1], Oacc[t][f], 0, 0, 0);
            }
        }
    }

    #pragma unroll
    for (int t = 0; t < 2; ++t) {
        const int qrow = qts[t] * TQ + wave * 16 + quad * 4;
        #pragma unroll
        for (int r = 0; r < 4; ++r) {
            float l = lrow[t][r];
            #pragma unroll
            for (int m = 1; m < 16; m <<= 1) l += __shfl_xor(l, m, 64);
            float invl = 1.f / l;
            #pragma unroll
            for (int f = 0; f < 4; ++f)
                o[baseO + (size_t)(qrow + r) * DMODEL + f * 16 + l16] = f2b(Oacc[t][f][r] * invl);
        }
    }
}

// ---------------- Host launcher ----------------
extern "C" void kernel_launch(void* const* d_in, const int* in_sizes, int n_in,
                              void* d_out, int out_size, void* d_ws, size_t ws_size,
                              hipStream_t stream) {
    const float* x      = (const float*)d_in[0];
    const float* wq     = (const float*)d_in[1];
    const float* wk     = (const float*)d_in[2];
    const float* wv     = (const float*)d_in[3];
    const float* wo     = (const float*)d_in[4];
    const float* w1     = (const float*)d_in[5];
    const float* b1     = (const float*)d_in[6];
    const float* w2     = (const float*)d_in[7];
    const float* b2     = (const float*)d_in[8];
    const float* gamma1 = (const float*)d_in[9];
    const float* beta1  = (const float*)d_in[10];
    const float* gamma2 = (const float*)d_in[11];
    const float* beta2  = (const float*)d_in[12];
    float* out = (float*)d_out;

    char* ws = (char*)d_ws;
    ushort* buf_xn   = (ushort*)ws;                              // 8192*768
    ushort* buf_attn = buf_xn;
    ushort* buf_qkv  = (ushort*)(ws + 12582912);                 // 8192*2304
    ushort* buf_h    = buf_qkv;                                  // 8192*3072
    ushort* w_qkv    = (ushort*)(ws + 12582912 + 50331648);      // 2304*768
    ushort* w_ot     = w_qkv + (size_t)QKVN * DMODEL;
    ushort* w_1t     = w_ot + (size_t)DMODEL * DMODEL;
    ushort* w_2t     = w_1t + (size_t)HID * DMODEL;
    // V^T lives in d_out (free until step 4; stream-serial)
    ushort* buf_vt   = (ushort*)d_out;

    convert_w4<<<dim3(DMODEL/32, DMODEL/32, 4), 256, 0, stream>>>(wq, wk, wv, wo, w_qkv);
    convert_w<<<dim3(HID/32,    DMODEL/32), 256, 0, stream>>>(w1, w_1t, DMODEL, HID);
    convert_w<<<dim3(DMODEL/32, HID/32),    256, 0, stream>>>(w2, w_2t, HID, DMODEL);

    // 1) xn1 = LN(x)
    ln_kernel<<<NROWS, 256, 0, stream>>>(x, gamma1, beta1, buf_xn);
    // 2) qkv = xn1 @ [wq|wk|wv], Q cols pre-scaled by 0.125 (N=2304 -> gemm_big)
    gemm_big<<<dim3(QKVN/HN, NROWS/HM), 256, 0, stream>>>(buf_xn, w_qkv, nullptr, nullptr,
                                                          nullptr, buf_qkv, NROWS, QKVN, DMODEL, 0, 1);
    // 2b) V -> V^T per head (into d_out scratch)
    transpose_v<<<dim3(SEQ/64, BATCH*NHEAD), 256, 0, stream>>>(buf_qkv + 2*DMODEL, buf_vt);
    // 3) flash attention (paired q-tiles, GLDS dbuf staging, fixed-max softmax)
    fattn_kernel<<<dim3(NQT/2, BATCH*NHEAD), 256, 0, stream>>>(buf_qkv, buf_qkv + DMODEL,
                                                               buf_vt, buf_attn, QKVN);
    // 4) x1 = x + attn @ wo (N=768 -> gemm_mfma, 768-block grid = 3/CU)
    gemm_mfma<<<dim3(DMODEL/GN, NROWS/GM), 256, 0, stream>>>(buf_attn, w_ot, nullptr, x,
                                                             out, nullptr, NROWS, DMODEL, DMODEL, 0, 0);
    // 5) xn2 = LN(x1)
    ln_kernel<<<NROWS, 256, 0, stream>>>(out, gamma2, beta2, buf_xn);
    // 6) h = relu(xn2 @ w1 + b1) (N=3072 -> gemm_big)
    gemm_big<<<dim3(HID/HN, NROWS/HM), 256, 0, stream>>>(buf_xn, w_1t, b1, nullptr,
                                                         nullptr, buf_h, NROWS, HID, DMODEL, 1, 0);
    // 7) out = x1 + h @ w2 + b2 (N=768 -> gemm_mfma)
    gemm_mfma<<<dim3(DMODEL/GN, NROWS/GM), 256, 0, stream>>>(buf_h, w_2t, b2, out,
                                                             out, nullptr, NROWS, DMODEL, HID, 0, 0);
}

// Round 7
// 394.203 us; speedup vs baseline: 1.0650x; 1.0650x over previous
//
#include <hip/hip_runtime.h>
#include <hip/hip_bf16.h>
#include <math.h>

// Problem constants (match reference)
#define BATCH 4
#define SEQ   2048
#define DMODEL 768
#define NHEAD 12
#define HS    64
#define HID   3072   // 4*DMODEL
#define NROWS (BATCH*SEQ)   // 8192
#define QKVN  (3*DMODEL)    // 2304
#define EPS   1e-6f

typedef __attribute__((ext_vector_type(8))) short bf16x8;
typedef __attribute__((ext_vector_type(4))) float f32x4;

__device__ inline ushort f2b(float f) {
    union { float f; unsigned u; } x; x.f = f;
    unsigned u = x.u;
    unsigned r = (u + 0x7FFFu + ((u >> 16) & 1u)) >> 16;
    return (ushort)r;
}

// async global->LDS, 16B per lane (m97)
#define GLDS16(g, l) __builtin_amdgcn_global_load_lds( \
    (const __attribute__((address_space(1))) void*)(g), \
    (__attribute__((address_space(3))) void*)(l), 16, 0, 0)

// ---------------- Weight convert+transpose: fp32 [K][N] -> bf16 [N][K] ----------------
__global__ __launch_bounds__(256) void convert_w4(const float* __restrict__ p0,
                                                  const float* __restrict__ p1,
                                                  const float* __restrict__ p2,
                                                  const float* __restrict__ p3,
                                                  ushort* __restrict__ out) {
    const float* srcs[4] = { p0, p1, p2, p3 };
    const float* in = srcs[blockIdx.z];
    ushort* dst = out + (size_t)blockIdx.z * DMODEL * DMODEL;
    __shared__ float tile[32][33];
    const int bx = blockIdx.x * 32;  // N
    const int by = blockIdx.y * 32;  // K
    const int tx = threadIdx.x & 31, ty = threadIdx.x >> 5;
    #pragma unroll
    for (int i = 0; i < 32; i += 8)
        tile[ty + i][tx] = in[(size_t)(by + ty + i) * DMODEL + bx + tx];
    __syncthreads();
    #pragma unroll
    for (int i = 0; i < 32; i += 8)
        dst[(size_t)(bx + ty + i) * DMODEL + by + tx] = f2b(tile[tx][ty + i]);
}

__global__ __launch_bounds__(256) void convert_w(const float* __restrict__ in,
                                                 ushort* __restrict__ out,
                                                 int K, int N) {
    __shared__ float tile[32][33];
    const int bx = blockIdx.x * 32;  // N
    const int by = blockIdx.y * 32;  // K
    const int tx = threadIdx.x & 31, ty = threadIdx.x >> 5;
    #pragma unroll
    for (int i = 0; i < 32; i += 8)
        tile[ty + i][tx] = in[(size_t)(by + ty + i) * N + bx + tx];
    __syncthreads();
    #pragma unroll
    for (int i = 0; i < 32; i += 8)
        out[(size_t)(bx + ty + i) * K + by + tx] = f2b(tile[tx][ty + i]);
}

// ---------------- V transpose: v[b][s][h*64+d] (stride QKVN) -> vt[(bh*64+d)][s] ----------------
__global__ __launch_bounds__(256) void transpose_v(const ushort* __restrict__ v,
                                                   ushort* __restrict__ vt) {
    const int st = blockIdx.x;   // key tile (64 rows)
    const int bh = blockIdx.y;
    const int b = bh / NHEAD, h = bh % NHEAD;
    const ushort* src = v + ((size_t)b * SEQ) * QKVN + h * HS;
    ushort* dst = vt + ((size_t)bh * HS) * SEQ;
    __shared__ ushort t[64][65];
    const int col = threadIdx.x & 63;
    const int r0  = (threadIdx.x >> 6) * 16;
    #pragma unroll
    for (int i = 0; i < 16; ++i)
        t[col][r0 + i] = src[(size_t)(st * 64 + r0 + i) * QKVN + col];
    __syncthreads();
    #pragma unroll
    for (int i = 0; i < 16; ++i)
        dst[(size_t)(r0 + i) * SEQ + st * 64 + col] = t[r0 + i][col];
}

// ---------------- LayerNorm (ddof=1), fp32 in -> bf16 out ----------------
__global__ __launch_bounds__(256) void ln_kernel(const float* __restrict__ x,
                                                 const float* __restrict__ gamma,
                                                 const float* __restrict__ beta,
                                                 ushort* __restrict__ out) {
    const int row = blockIdx.x;
    const float* xr = x + (size_t)row * DMODEL;
    float s = 0.f, s2 = 0.f;
    for (int i = threadIdx.x; i < DMODEL; i += 256) {
        float v = xr[i];
        s += v; s2 += v * v;
    }
    for (int off = 32; off > 0; off >>= 1) {
        s  += __shfl_down(s,  off, 64);
        s2 += __shfl_down(s2, off, 64);
    }
    __shared__ float shs[4], shs2[4];
    int wid = threadIdx.x >> 6, lane = threadIdx.x & 63;
    if (lane == 0) { shs[wid] = s; shs2[wid] = s2; }
    __syncthreads();
    __shared__ float smean, srstd;
    if (threadIdx.x == 0) {
        float S  = shs[0] + shs[1] + shs[2] + shs[3];
        float S2 = shs2[0] + shs2[1] + shs2[2] + shs2[3];
        float mean = S / DMODEL;
        float var  = (S2 - DMODEL * mean * mean) / (DMODEL - 1);
        smean = mean;
        srstd = rsqrtf(var + EPS);
    }
    __syncthreads();
    float mean = smean, rstd = srstd;
    ushort* orow = out + (size_t)row * DMODEL;
    for (int i = threadIdx.x; i < DMODEL; i += 256) {
        orow[i] = f2b(gamma[i] * (xr[i] - mean) * rstd + beta[i]);
    }
}

// ---------------- gemm_mfma: 64x128 tile, BK=64, per-wave 32x64 (kept for N=768) ----------------
// r10 geometry: 48KB dbuf, 3 blocks/CU; grids with N=768 are 768 blocks = 3/CU.
#define GN 128
#define GK 64
#define GM 64
__global__ __launch_bounds__(256, 3) void gemm_mfma(const ushort* __restrict__ A,
                                                    const ushort* __restrict__ Bt,
                                                    const float* __restrict__ bias,
                                                    const float* __restrict__ res,
                                                    float* __restrict__ C,
                                                    ushort* __restrict__ Cb,
                                                    int M, int N, int K, int do_relu,
                                                    int scale_q) {
    __shared__ ushort As[2][GM * GK];
    __shared__ ushort Bs[2][GN * GK];
    const int tid  = threadIdx.x;
    const int lane = tid & 63, wave = tid >> 6;
    const int l16  = lane & 15, quad = lane >> 4;
    const int wr = wave >> 1, wc = wave & 1;

    // XCD-aware swizzle: give each XCD a contiguous row-major chunk
    const int nwg = gridDim.x * gridDim.y;
    int id = blockIdx.y * gridDim.x + blockIdx.x;
    if ((nwg & 7) == 0) {
        const int chunk = nwg >> 3;
        id = (id & 7) * chunk + (id >> 3);
    }
    const int bx = id % gridDim.x;
    const int by = id / gridDim.x;
    const int row0 = by * GM, col0 = bx * GN;

    f32x4 acc[2][4];
    #pragma unroll
    for (int i = 0; i < 2; ++i)
        #pragma unroll
        for (int j = 0; j < 4; ++j) acc[i][j] = (f32x4){0.f, 0.f, 0.f, 0.f};

    // staging: LDS chunk c=(m<<3)|j  <-  global chunk j^(m&7) of row m
    const ushort* Asrc[2];
    const ushort* Bsrc[4];
    #pragma unroll
    for (int i = 0; i < 2; ++i) {
        int c = tid + i * 256, m = c >> 3, j = c & 7;
        Asrc[i] = A + (size_t)(row0 + m) * K + (j ^ (m & 7)) * 8;
    }
    #pragma unroll
    for (int i = 0; i < 4; ++i) {
        int c = tid + i * 256, m = c >> 3, j = c & 7;
        Bsrc[i] = Bt + (size_t)(col0 + m) * K + (j ^ (m & 7)) * 8;
    }

    const int nk = K / GK;
    // prologue: stage K-tile 0 into buf 0
    #pragma unroll
    for (int i = 0; i < 2; ++i) GLDS16(Asrc[i], &As[0][(tid + i * 256) * 8]);
    #pragma unroll
    for (int i = 0; i < 4; ++i)  GLDS16(Bsrc[i], &Bs[0][(tid + i * 256) * 8]);

    for (int kt = 0; kt < nk; ++kt) {
        const int p = kt & 1;
        __syncthreads();   // drains buf[p] loads; all waves done reading buf[p^1]
        if (kt + 1 < nk) {
            const int k1 = (kt + 1) * GK;
            #pragma unroll
            for (int i = 0; i < 2; ++i) GLDS16(Asrc[i] + k1, &As[p ^ 1][(tid + i * 256) * 8]);
            #pragma unroll
            for (int i = 0; i < 4; ++i)  GLDS16(Bsrc[i] + k1, &Bs[p ^ 1][(tid + i * 256) * 8]);
        }

        #pragma unroll
        for (int s = 0; s < 2; ++s) {
            bf16x8 af[2], bfr[4];
            #pragma unroll
            for (int i = 0; i < 2; ++i) {
                int m = wr * 32 + i * 16 + l16;
                af[i] = *(const bf16x8*)&As[p][(m * 8 + (((s << 2) | quad) ^ (m & 7))) * 8];
            }
            #pragma unroll
            for (int j = 0; j < 4; ++j) {
                int n = wc * 64 + j * 16 + l16;
                bfr[j] = *(const bf16x8*)&Bs[p][(n * 8 + (((s << 2) | quad) ^ (n & 7))) * 8];
            }
            #pragma unroll
            for (int i = 0; i < 2; ++i)
                #pragma unroll
                for (int j = 0; j < 4; ++j)
                    acc[i][j] = __builtin_amdgcn_mfma_f32_16x16x32_bf16(af[i], bfr[j], acc[i][j], 0, 0, 0);
        }
    }

    // epilogue: C/D layout col=l16, row=quad*4+r
    #pragma unroll
    for (int i = 0; i < 2; ++i) {
        #pragma unroll
        for (int r = 0; r < 4; ++r) {
            int row = row0 + wr * 32 + i * 16 + quad * 4 + r;
            #pragma unroll
            for (int j = 0; j < 4; ++j) {
                int col = col0 + wc * 64 + j * 16 + l16;
                float v = acc[i][j][r];
                if (bias) v += bias[col];
                if (do_relu) v = fmaxf(v, 0.f);
                if (scale_q && col < DMODEL) v *= 0.125f;  // fold 1/sqrt(hs) into Q
                if (res) v += res[(size_t)row * N + col];
                if (Cb) Cb[(size_t)row * N + col] = f2b(v);
                else    C [(size_t)row * N + col] = v;
            }
        }
    }
}

// ---------------- gemm_big: 128x128, BK=32, 512 threads, tri-buffer + counted vmcnt ----------------
// r14: r6 (tri-buffer, counted vmcnt, 256t) fixed the drain (92.5->84) but
// MfmaUtil stuck ~18% and occupancy pinned at ~30% (3 waves/SIMD) all
// session. Arithmetic: 1400 cy/block-K-step vs 310 cy MFMA + ~500 LDS +
// ~270 VALU -> latency-bound with too few runnable waves per SIMD.
// Single-variable change: 512 threads / 8 waves (per-wave 32x64, acc
// halves), same tile/BK/layout/schedule. 48KB LDS -> 3 blocks/CU ->
// 24 waves/CU = 6 waves/SIMD (launch_bounds(512,6), VGPR cap ~85).
// STAGE = 1 A chunk + 1 B chunk per thread -> vmcnt(2) counted wait.
// Predicted: occupancy ~30->~60%, MfmaUtil 18->28+, MLP1 84->~57.
// Tripwires: WRITE_SIZE jump = spill at cap -> (512,5); occupancy up but
// time flat -> latency not binding -> port 8-phase 256^2 template next.
#define HM 128
#define HN 128
#define HK 32
__global__ __launch_bounds__(512, 6) void gemm_big(const ushort* __restrict__ A,
                                                   const ushort* __restrict__ Bt,
                                                   const float* __restrict__ bias,
                                                   const float* __restrict__ res,
                                                   float* __restrict__ C,
                                                   ushort* __restrict__ Cb,
                                                   int M, int N, int K, int do_relu,
                                                   int scale_q) {
    __shared__ ushort As[3][HM * HK];   // 3 x 8 KB
    __shared__ ushort Bs[3][HN * HK];   // 3 x 8 KB  -> 48 KB total
    const int tid  = threadIdx.x;
    const int lane = tid & 63, wave = tid >> 6;   // 0..7
    const int l16  = lane & 15, quad = lane >> 4;
    const int wr = wave & 3, wc = wave >> 2;      // 4x2 wave grid, 32x64/wave

    const int nwg = gridDim.x * gridDim.y;
    int id = blockIdx.y * gridDim.x + blockIdx.x;
    if ((nwg & 7) == 0) {
        const int chunk = nwg >> 3;
        id = (id & 7) * chunk + (id >> 3);
    }
    const int bx = id % gridDim.x;
    const int by = id / gridDim.x;
    const int row0 = by * HM, col0 = bx * HN;

    f32x4 acc[2][4];
    #pragma unroll
    for (int i = 0; i < 2; ++i)
        #pragma unroll
        for (int j = 0; j < 4; ++j) acc[i][j] = (f32x4){0.f, 0.f, 0.f, 0.f};

    // staging: LDS chunk c = lr*8+pos holds global (m = 2*lr + (p>>2), j = p&3)
    // where p = pos ^ (lr&7)   [zero-conflict row-pair layout, verified r5/r6]
    // 512 chunks per matrix, 512 threads -> 1 A + 1 B chunk per thread
    const ushort* Asrc;
    const ushort* Bsrc;
    {
        int c = tid;
        int lr = c >> 3, pp = (c & 7) ^ (lr & 7);
        int m = lr * 2 + (pp >> 2), j = pp & 3;
        Asrc = A  + (size_t)(row0 + m) * K + j * 8;
        Bsrc = Bt + (size_t)(col0 + m) * K + j * 8;
    }

    const int nk = K / HK;   // K=768 -> 24

    // 2 vmcnt-instructions per tile-stage (A,B)
#define STAGE_BIG(kt, b) do { \
    const int _k = (kt) * HK; \
    GLDS16(Asrc + _k, &As[b][tid * 8]); \
    GLDS16(Bsrc + _k, &Bs[b][tid * 8]); \
} while (0)

    STAGE_BIG(0, 0);
    STAGE_BIG(1, 1);

    int pc = 0, pn = 1, ps = 2;   // compute / next / stage-target buffers
    for (int t = 0; t < nk; ++t) {
        // wait tile t only: tile t+1's 2 loads stay in flight
        if (t + 1 < nk) asm volatile("s_waitcnt vmcnt(2)" ::: "memory");
        else            asm volatile("s_waitcnt vmcnt(0)" ::: "memory");
        __builtin_amdgcn_s_barrier();
        if (t + 2 < nk) STAGE_BIG(t + 2, ps);

        bf16x8 af[2], bfr[4];
        #pragma unroll
        for (int i = 0; i < 2; ++i) {
            int m = wr * 32 + i * 16 + l16;
            int ch = (m >> 1) * 8 + ((((m & 1) << 2) | quad) ^ ((m >> 1) & 7));
            af[i] = *(const bf16x8*)&As[pc][ch * 8];
        }
        #pragma unroll
        for (int j = 0; j < 4; ++j) {
            int n = wc * 64 + j * 16 + l16;
            int ch = (n >> 1) * 8 + ((((n & 1) << 2) | quad) ^ ((n >> 1) & 7));
            bfr[j] = *(const bf16x8*)&Bs[pc][ch * 8];
        }
        #pragma unroll
        for (int i = 0; i < 2; ++i)
            #pragma unroll
            for (int j = 0; j < 4; ++j)
                acc[i][j] = __builtin_amdgcn_mfma_f32_16x16x32_bf16(af[i], bfr[j], acc[i][j], 0, 0, 0);

        int tmp = pc; pc = pn; pn = ps; ps = tmp;
    }

    // epilogue: C/D layout col=l16, row=quad*4+r
    #pragma unroll
    for (int i = 0; i < 2; ++i) {
        #pragma unroll
        for (int r = 0; r < 4; ++r) {
            int row = row0 + wr * 32 + i * 16 + quad * 4 + r;
            #pragma unroll
            for (int j = 0; j < 4; ++j) {
                int col = col0 + wc * 64 + j * 16 + l16;
                float v = acc[i][j][r];
                if (bias) v += bias[col];
                if (do_relu) v = fmaxf(v, 0.f);
                if (scale_q && col < DMODEL) v *= 0.125f;  // fold 1/sqrt(hs) into Q
                if (res) v += res[(size_t)row * N + col];
                if (Cb) Cb[(size_t)row * N + col] = f2b(v);
                else    C [(size_t)row * N + col] = v;
            }
        }
    }
}

// ---------------- Flash attention: paired q-tiles, GLDS staging, dbuf ----------------
#define TQ 64
#define TK 64
#define PPAD 72
#define NQT (SEQ / TQ)   // 32

__global__ __launch_bounds__(256, 3) void fattn_kernel(const ushort* __restrict__ q,
                                                       const ushort* __restrict__ k,
                                                       const ushort* __restrict__ vt,
                                                       ushort* __restrict__ o,
                                                       int ldqkv) {
    const int pair = blockIdx.x;             // 0..15
    const int qts[2] = { pair, NQT - 1 - pair };
    const int bh = blockIdx.y;
    const int b = bh / NHEAD, h = bh % NHEAD;
    const int tid  = threadIdx.x;
    const int wave = tid >> 6;
    const int lane = tid & 63;
    const int l16  = lane & 15;
    const int quad = lane >> 4;

    __shared__ ushort Ks[2][TK * 64];    // 8 KB per buffer, packed [key][8 chunks]
    __shared__ ushort Vs[2][HS * 64];    // 8 KB per buffer, packed [d][8 chunks]
    __shared__ ushort Ps[4][16][PPAD];   // per-wave P[q][key] (wave-private)

    const size_t base  = ((size_t)b * SEQ) * ldqkv + (size_t)h * HS;
    const size_t baseO = ((size_t)b * SEQ) * DMODEL + (size_t)h * HS;
    const ushort* vth = vt + ((size_t)bh * HS) * SEQ;

    const int r0 = tid >> 3, j0 = (tid & 7) ^ (r0 & 7);
    const int r1 = (tid + 256) >> 3, j1 = (tid & 7) ^ (r1 & 7);
    const ushort* Ksrc0 = k + base + (size_t)r0 * ldqkv + j0 * 8;
    const ushort* Ksrc1 = k + base + (size_t)r1 * ldqkv + j1 * 8;
    const ushort* Vsrc0 = vth + (size_t)r0 * SEQ + j0 * 8;
    const ushort* Vsrc1 = vth + (size_t)r1 * SEQ + j1 * 8;

    bf16x8 qf[2][2];
    #pragma unroll
    for (int t = 0; t < 2; ++t) {
        int qrow = qts[t] * TQ + wave * 16 + l16;
        const ushort* qp = q + base + (size_t)qrow * ldqkv + quad * 8;
        qf[t][0] = *(const bf16x8*)(qp);
        qf[t][1] = *(const bf16x8*)(qp + 32);
    }

    f32x4 Oacc[2][4];
    float lrow[2][4];
    #pragma unroll
    for (int t = 0; t < 2; ++t) {
        #pragma unroll
        for (int f = 0; f < 4; ++f) Oacc[t][f] = (f32x4){0.f, 0.f, 0.f, 0.f};
        #pragma unroll
        for (int r = 0; r < 4; ++r) lrow[t][r] = 0.f;
    }

    const int ktiles = qts[1] + 1;
    GLDS16(Ksrc0, &Ks[0][tid * 8]);
    GLDS16(Ksrc1, &Ks[0][(tid + 256) * 8]);
    GLDS16(Vsrc0, &Vs[0][tid * 8]);
    GLDS16(Vsrc1, &Vs[0][(tid + 256) * 8]);

    for (int kt = 0; kt < ktiles; ++kt) {
        const int p = kt & 1;
        __syncthreads();   // drains buf[p] (in flight since last compute phase)
        if (kt + 1 < ktiles) {
            const size_t ko = (size_t)(kt + 1) * TK;
            GLDS16(Ksrc0 + ko * ldqkv, &Ks[p ^ 1][tid * 8]);
            GLDS16(Ksrc1 + ko * ldqkv, &Ks[p ^ 1][(tid + 256) * 8]);
            GLDS16(Vsrc0 + ko,         &Vs[p ^ 1][tid * 8]);
            GLDS16(Vsrc1 + ko,         &Vs[p ^ 1][(tid + 256) * 8]);
        }

        bf16x8 kb[4][2], vb[4][2];
        #pragma unroll
        for (int f = 0; f < 4; ++f) {
            int row = f * 16 + l16;
            kb[f][0] = *(const bf16x8*)&Ks[p][(row * 8 + (quad ^ (row & 7))) * 8];
            kb[f][1] = *(const bf16x8*)&Ks[p][(row * 8 + ((4 | quad) ^ (row & 7))) * 8];
            vb[f][0] = *(const bf16x8*)&Vs[p][(row * 8 + (quad ^ (row & 7))) * 8];
            vb[f][1] = *(const bf16x8*)&Vs[p][(row * 8 + ((4 | quad) ^ (row & 7))) * 8];
        }

        #pragma unroll
        for (int t = 0; t < 2; ++t) {
            const int qt = qts[t];
            if (kt > qt) continue;   // wave-uniform; only t=0 can skip

            f32x4 S[4];
            #pragma unroll
            for (int f = 0; f < 4; ++f) {
                f32x4 a = (f32x4){0.f, 0.f, 0.f, 0.f};
                a = __builtin_amdgcn_mfma_f32_16x16x32_bf16(qf[t][0], kb[f][0], a, 0, 0, 0);
                a = __builtin_amdgcn_mfma_f32_16x16x32_bf16(qf[t][1], kb[f][1], a, 0, 0, 0);
                S[f] = a;
            }

            const int qrow_base = qt * TQ + wave * 16 + quad * 4;
            if (kt == qt) {
                #pragma unroll
                for (int f = 0; f < 4; ++f) {
                    int key = kt * TK + f * 16 + l16;
                    #pragma unroll
                    for (int r = 0; r < 4; ++r)
                        if (key > qrow_base + r) S[f][r] = -INFINITY;
                }
            }

            #pragma unroll
            for (int f = 0; f < 4; ++f) {
                #pragma unroll
                for (int r = 0; r < 4; ++r) {
                    float pv = __expf(S[f][r]);
                    S[f][r] = pv;
                    lrow[t][r] += pv;
                }
            }

            #pragma unroll
            for (int f = 0; f < 4; ++f)
                #pragma unroll
                for (int r = 0; r < 4; ++r)
                    Ps[wave][quad * 4 + r][f * 16 + l16] = f2b(S[f][r]);

            bf16x8 pa0 = *(const bf16x8*)&Ps[wave][l16][quad * 8];
            bf16x8 pa1 = *(const bf16x8*)&Ps[wave][l16][32 + quad * 8];
            #pragma unroll
            for (int f = 0; f < 4; ++f) {
                Oacc[t][f] = __builtin_amdgcn_mfma_f32_16x16x32_bf16(pa0, vb[f][0], Oacc[t][f], 0, 0, 0);
                Oacc[t][f] = __builtin_amdgcn_mfma_f32_16x16x32_bf16(pa1, vb[f][1], Oacc[t][f], 0, 0, 0);
            }
        }
    }

    #pragma unroll
    for (int t = 0; t < 2; ++t) {
        const int qrow = qts[t] * TQ + wave * 16 + quad * 4;
        #pragma unroll
        for (int r = 0; r < 4; ++r) {
            float l = lrow[t][r];
            #pragma unroll
            for (int m = 1; m < 16; m <<= 1) l += __shfl_xor(l, m, 64);
            float invl = 1.f / l;
            #pragma unroll
            for (int f = 0; f < 4; ++f)
                o[baseO + (size_t)(qrow + r) * DMODEL + f * 16 + l16] = f2b(Oacc[t][f][r] * invl);
        }
    }
}

// ---------------- Host launcher ----------------
extern "C" void kernel_launch(void* const* d_in, const int* in_sizes, int n_in,
                              void* d_out, int out_size, void* d_ws, size_t ws_size,
                              hipStream_t stream) {
    const float* x      = (const float*)d_in[0];
    const float* wq     = (const float*)d_in[1];
    const float* wk     = (const float*)d_in[2];
    const float* wv     = (const float*)d_in[3];
    const float* wo     = (const float*)d_in[4];
    const float* w1     = (const float*)d_in[5];
    const float* b1     = (const float*)d_in[6];
    const float* w2     = (const float*)d_in[7];
    const float* b2     = (const float*)d_in[8];
    const float* gamma1 = (const float*)d_in[9];
    const float* beta1  = (const float*)d_in[10];
    const float* gamma2 = (const float*)d_in[11];
    const float* beta2  = (const float*)d_in[12];
    float* out = (float*)d_out;

    char* ws = (char*)d_ws;
    ushort* buf_xn   = (ushort*)ws;                              // 8192*768
    ushort* buf_attn = buf_xn;
    ushort* buf_qkv  = (ushort*)(ws + 12582912);                 // 8192*2304
    ushort* buf_h    = buf_qkv;                                  // 8192*3072
    ushort* w_qkv    = (ushort*)(ws + 12582912 + 50331648);      // 2304*768
    ushort* w_ot     = w_qkv + (size_t)QKVN * DMODEL;
    ushort* w_1t     = w_ot + (size_t)DMODEL * DMODEL;
    ushort* w_2t     = w_1t + (size_t)HID * DMODEL;
    // V^T lives in d_out (free until step 4; stream-serial)
    ushort* buf_vt   = (ushort*)d_out;

    convert_w4<<<dim3(DMODEL/32, DMODEL/32, 4), 256, 0, stream>>>(wq, wk, wv, wo, w_qkv);
    convert_w<<<dim3(HID/32,    DMODEL/32), 256, 0, stream>>>(w1, w_1t, DMODEL, HID);
    convert_w<<<dim3(DMODEL/32, HID/32),    256, 0, stream>>>(w2, w_2t, HID, DMODEL);

    // 1) xn1 = LN(x)
    ln_kernel<<<NROWS, 256, 0, stream>>>(x, gamma1, beta1, buf_xn);
    // 2) qkv = xn1 @ [wq|wk|wv], Q cols pre-scaled by 0.125 (N=2304 -> gemm_big, 512t)
    gemm_big<<<dim3(QKVN/HN, NROWS/HM), 512, 0, stream>>>(buf_xn, w_qkv, nullptr, nullptr,
                                                          nullptr, buf_qkv, NROWS, QKVN, DMODEL, 0, 1);
    // 2b) V -> V^T per head (into d_out scratch)
    transpose_v<<<dim3(SEQ/64, BATCH*NHEAD), 256, 0, stream>>>(buf_qkv + 2*DMODEL, buf_vt);
    // 3) flash attention (paired q-tiles, GLDS dbuf staging, fixed-max softmax)
    fattn_kernel<<<dim3(NQT/2, BATCH*NHEAD), 256, 0, stream>>>(buf_qkv, buf_qkv + DMODEL,
                                                               buf_vt, buf_attn, QKVN);
    // 4) x1 = x + attn @ wo (N=768 -> gemm_mfma, 768-block grid = 3/CU)
    gemm_mfma<<<dim3(DMODEL/GN, NROWS/GM), 256, 0, stream>>>(buf_attn, w_ot, nullptr, x,
                                                             out, nullptr, NROWS, DMODEL, DMODEL, 0, 0);
    // 5) xn2 = LN(x1)
    ln_kernel<<<NROWS, 256, 0, stream>>>(out, gamma2, beta2, buf_xn);
    // 6) h = relu(xn2 @ w1 + b1) (N=3072 -> gemm_big, 512t)
    gemm_big<<<dim3(HID/HN, NROWS/HM), 512, 0, stream>>>(buf_xn, w_1t, b1, nullptr,
                                                         nullptr, buf_h, NROWS, HID, DMODEL, 1, 0);
    // 7) out = x1 + h @ w2 + b2 (N=768 -> gemm_mfma)
    gemm_mfma<<<dim3(DMODEL/GN, NROWS/GM), 256, 0, stream>>>(buf_h, w_2t, b2, out,
                                                             out, nullptr, NROWS, DMODEL, HID, 0, 0);
}